// Round 3
// baseline (227.382 us; speedup 1.0000x reference)
//
#include <hip/hip_runtime.h>

typedef int v4i __attribute__((ext_vector_type(4)));

#define QMAX 127.0f

// ---- workspace layout ----
// xq  : int8 padded, swizzled [16][66][66 px][5 c5][4 slots][16]
//       slot s of (col,c5) holds logical ci-chunk s ^ ((col>>1)&3)
// wq2 : int8 fragment-order [9][5][20cog][64lane][16]
// bi  : float [320]
#define XQ_BYTES 22302720
#define WQ_BYTES 921600

__device__ __forceinline__ float clampf(float v, float lo, float hi) {
    return fminf(fmaxf(v, lo), hi);
}

// Bit-exact fast round(v/step): reciprocal multiply, exact-division fallback
// only near half-integer boundaries (trigger ~7e-4; 50x error margin).
__device__ __forceinline__ float qround(float v, float step, float inv) {
    float t = v * inv;
    float r = rintf(t);
    float d = fabsf(t - r);
    if (fabsf(d - 0.5f) < fabsf(t) * 1e-5f + 1e-5f)
        r = rintf(v / step);
    return r;
}

__device__ __forceinline__ void gload_lds16(const char* g, char* l) {
    __builtin_amdgcn_global_load_lds(
        (const __attribute__((address_space(1))) void*)g,
        (__attribute__((address_space(3))) void*)l, 16, 0, 0);
}

__device__ __forceinline__ v4i mfma_i8(v4i a, v4i b, v4i c) {
    return __builtin_amdgcn_mfma_i32_16x16x64_i8(a, b, c, 0, 0, 0);
}

// ---------------------------------------------------------------------------
// Fused producer kernel:
//   blocks [0,1024)    : x quantize (block = (h,b)), long pole -> first
//   blocks [1024,1924) : wq2 quantize, 4 bytes/thread, dword stores
//   blocks [1924,2249) : xq halo zeroing
//   block  2249        : bias requant
// ---------------------------------------------------------------------------
__global__ __launch_bounds__(256) void fused_prep_kernel(
    const float* __restrict__ x, const float* __restrict__ w,
    const float* __restrict__ bias,
    const float* __restrict__ step_x_p, const float* __restrict__ step_w_p,
    const float* __restrict__ step_b_p, const float* __restrict__ shift_p,
    char* __restrict__ xq, char* __restrict__ wq2, float* __restrict__ bi)
{
    __shared__ float F[64 * 65];   // [ci_local][w], stride 65 floats
    const int bid = blockIdx.x;
    const int t = threadIdx.x;

    if (bid < 1024) {
        // ---- x quantize: one block per (h,b); writes row h+1 interior ----
        const int h = bid & 63;
        const int b = bid >> 6;
        const float step = *step_x_p;
        const float inv  = 1.0f / step;
        const int wcol = t >> 2;       // output col-1 (0..63)
        const int cg   = t & 3;        // logical 16-ci chunk within c5
        v4i vals[5];

        for (int c5 = 0; c5 < 5; ++c5) {
            {
                const int r = t >> 4, c = (t & 15) * 4;
                const float* src = x + (((size_t)(b * 320 + c5 * 64) * 64 + h) * 64);
#pragma unroll
                for (int i = 0; i < 4; ++i) {
                    const int row = r + i * 16;
                    *(float4*)&F[row * 65 + c] =
                        *(const float4*)(src + (size_t)row * 4096 + c);
                }
            }
            __syncthreads();
            int dws[4];
#pragma unroll
            for (int j = 0; j < 4; ++j) {
                int word = 0;
#pragma unroll
                for (int k = 0; k < 4; ++k) {
                    float v = F[(cg * 16 + j * 4 + k) * 65 + wcol];
                    int xi = (int)clampf(qround(v, step, inv), -QMAX, QMAX);
                    word |= (xi & 0xFF) << (8 * k);
                }
                dws[j] = word;
            }
            vals[c5] = (v4i){dws[0], dws[1], dws[2], dws[3]};
            __syncthreads();
        }

        const int col = wcol + 1;
        const int key = (col >> 1) & 3;
        char* base = xq + ((size_t)(b * 66 + (h + 1)) * 66 + col) * 320;
#pragma unroll
        for (int c5 = 0; c5 < 5; ++c5)
            *(v4i*)(base + c5 * 64 + (((cg ^ key)) << 4)) = vals[c5];

    } else if (bid < 1924) {
        // ---- weight quantize into MFMA fragment order, 4 bytes/thread ----
        const int t4  = (bid - 1024) * 256 + t;   // [0, 230400)
        const int tid = t4 * 4;
        const float step = *step_w_p;
        const float inv  = 1.0f / step;
        const int p    = tid / 102400;
        const int r    = tid - p * 102400;
        const int c5   = r / 20480;
        const int r2   = r - c5 * 20480;
        const int cog  = r2 >> 10;
        const int r3   = r2 & 1023;
        const int lane = r3 >> 4, j0 = r3 & 15;   // j0 in {0,4,8,12}
        const int co  = cog * 16 + (lane & 15);
        const int ci0 = c5 * 64 + (lane >> 4) * 16 + j0;
        const float* wsrc = w + (size_t)co * 2880 + ci0 * 9 + p;
        int word = 0;
#pragma unroll
        for (int k = 0; k < 4; ++k) {
            int q = (int)clampf(qround(wsrc[k * 9], step, inv), -QMAX, QMAX);
            word |= (q & 0xFF) << (8 * k);
        }
        *(int*)(wq2 + tid) = word;
    } else if (bid < 2249) {
        // ---- halo zeroing ----
        int tid = (bid - 1924) * 256 + t;
        if (tid < 83200) {
            int b = tid / 5200;
            int r = tid - b * 5200;
            int px = r / 20;
            int ck = (r - px * 20) * 16;
            int row, col;
            if (px < 66)       { row = 0;  col = px; }
            else if (px < 132) { row = 65; col = px - 66; }
            else { int e = px - 132; row = 1 + (e >> 1); col = (e & 1) * 65; }
            size_t off = ((size_t)(b * 66 + row) * 66 + col) * 320 + ck;
            v4i z = {0, 0, 0, 0};
            *(v4i*)&xq[off] = z;
        }
    } else {
        // ---- bias requant ----
        const float step_b = *step_b_p;
        const float xs = 1.0f / *step_x_p;
        const float ws = 1.0f / *step_w_p;
        const float shift = *shift_p;
#pragma unroll
        for (int co = t; co < 320; co += 256) {
            float b_deq = clampf(rintf(bias[co] / step_b), -QMAX, QMAX) * step_b;
            float v = ((b_deq * shift) * xs) * ws;
            bi[co] = clampf(rintf(v), -QMAX, QMAX);
        }
    }
}

// ---------------------------------------------------------------------------
// Implicit-GEMM conv, v_mfma_i32_16x16x64_i8.
// Grid 640 (all resident at 3 blocks/CU): each block processes TWO ptiles
// (ptile0 and ptile0+128, i.e. batch b and b+8, same rows) with a seamless
// double-buffer pipeline across the pair: ptile2's first B-tile DMA issues
// during ptile1's last c5 compute, ptile1's epilogue stores drain under
// ptile2's MFMAs, and one prologue drain per pair is eliminated.
// XCD remap unchanged: id%8 = (ptile&7) -> the 5 co-tiles of a ptile-pair
// run adjacent in time on one XCD -> xq L2-hot across co-tiles.
// Pipeline hazard audit (u = global stage index, 10 stages):
//   u5->B[1], u6->B[0], u7->B[1], u8->B[0], u9->B[1]; every LDS
//   write-after-read is separated by a __syncthreads (vmcnt drain).
// ---------------------------------------------------------------------------
__global__ __launch_bounds__(256, 3) void conv_mfma_kernel(
    const char* __restrict__ xq, const char* __restrict__ wq2,
    const float* __restrict__ bi, const float* __restrict__ shift_p,
    float* __restrict__ out)
{
    __shared__ __attribute__((aligned(16))) char B_lds[2][25344]; // 6 rows x 66 x 64

    const int t  = threadIdx.x;
    const int id = blockIdx.x;           // 0..639
    // id = (ptile&7) + 8*bx + 40*(ptile>>3), ptile in [0,128)
    const int g  = id / 40;
    const int r  = id - g * 40;
    const int bx = r >> 3;               // co tile 0..4
    const int ptile = (g << 3) | (r & 7);

    const int co0 = bx * 64;
    const int b0 = ptile >> 4;           // [0,8); second ptile = b0+8
    const int h0 = (ptile & 15) * 4;

    const int wave = t >> 6, lane = t & 63;
    const int quad = lane >> 4, l15 = lane & 15;

    const char* xbase0 = xq + ((size_t)(b0 * 66 + h0) * 66) * 320;
    const char* xbase1 = xq + ((size_t)((b0 + 8) * 66 + h0) * 66) * 320;

    const float shift = *shift_p;

    v4i acc[4][4] = {};

    auto stage = [&](const char* xb, int ci0, char* dst) {
        for (int c = t; c < 1584; c += 256) {
            const char* gp = xb + (c >> 2) * 320 + ci0 + ((c & 3) << 4);
            gload_lds16(gp, &dst[(c - lane) * 16]);
        }
    };

    auto compute_c5 = [&](int c5, const char* Bc) {
        const char* wp = wq2 + (c5 * 20 + bx * 4) * 1024 + lane * 16;
        // A double-buffer: prefetch p+1's 4 fragments while p's MFMAs run.
        v4i areg[2][4];
#pragma unroll
        for (int cs = 0; cs < 4; ++cs)
            areg[0][cs] = *(const v4i*)(wp + cs * 1024);
#pragma unroll
        for (int p = 0; p < 9; ++p) {
            const int dh = p / 3, dw = p - dh * 3;
            if (p < 8) {
#pragma unroll
                for (int cs = 0; cs < 4; ++cs)
                    areg[(p + 1) & 1][cs] =
                        *(const v4i*)(wp + (p + 1) * 102400 + cs * 1024);
            }
            const int prow = wave + dh;
            auto bread = [&](int i) -> v4i {
                const int col = i * 16 + l15 + dw;
                const int key = (col >> 1) & 3;
                return *(const v4i*)&Bc[(prow * 66 + col) * 64 +
                                        ((quad ^ key) << 4)];
            };
            v4i bf = bread(0);
#pragma unroll
            for (int i = 0; i < 4; ++i) {
                v4i bcur = bf;
                if (i < 3) bf = bread(i + 1);
                __builtin_amdgcn_s_setprio(1);
#pragma unroll
                for (int cs = 0; cs < 4; ++cs)
                    acc[cs][i] = mfma_i8(areg[p & 1][cs], bcur, acc[cs][i]);
                __builtin_amdgcn_s_setprio(0);
            }
        }
    };

    auto epilogue = [&](int b) {
        const int h = h0 + wave;
#pragma unroll
        for (int cs = 0; cs < 4; ++cs) {
#pragma unroll
            for (int reg = 0; reg < 4; ++reg) {
                const int co = co0 + cs * 16 + quad * 4 + reg;
                const float bv = bi[co];
                float* orow = out + (((size_t)(b * 320 + co) * 64) + h) * 64;
#pragma unroll
                for (int i = 0; i < 4; ++i) {
                    float y  = (float)acc[cs][i][reg];
                    float ys = clampf(rintf(y * shift), -QMAX, QMAX);
                    orow[i * 16 + l15] = clampf(ys + bv, -QMAX, QMAX);
                }
            }
        }
    };

    // prologue: stage ptile1 c5=0 into buffer 0
    stage(xbase0, 0, B_lds[0]);
    __syncthreads();

    // ---- ptile 1 (u = 0..4, buffer u&1) ----
    for (int c5 = 0; c5 < 5; ++c5) {
        if (c5 < 4) stage(xbase0, (c5 + 1) * 64, B_lds[(c5 + 1) & 1]);
        else        stage(xbase1, 0,             B_lds[1]);   // u=5
        compute_c5(c5, B_lds[c5 & 1]);
        __syncthreads();
    }

    // issue u=6 DMA before the epilogue so it overlaps the store burst
    stage(xbase1, 64, B_lds[0]);
    epilogue(b0);

#pragma unroll
    for (int cs = 0; cs < 4; ++cs)
#pragma unroll
        for (int i = 0; i < 4; ++i)
            acc[cs][i] = (v4i){0, 0, 0, 0};

    // ---- ptile 2 (u = 5..9, buffer u&1 -> compute buf[(c5+1)&1]) ----
    for (int c5 = 0; c5 < 5; ++c5) {
        if (c5 >= 1 && c5 < 4) stage(xbase1, (c5 + 1) * 64, B_lds[c5 & 1]);
        compute_c5(c5, B_lds[(c5 + 1) & 1]);
        if (c5 < 4) __syncthreads();
    }
    epilogue(b0 + 8);
}

extern "C" void kernel_launch(void* const* d_in, const int* in_sizes, int n_in,
                              void* d_out, int out_size, void* d_ws, size_t ws_size,
                              hipStream_t stream) {
    const float* x      = (const float*)d_in[0];
    const float* w      = (const float*)d_in[1];
    const float* bias   = (const float*)d_in[2];
    const float* step_x = (const float*)d_in[3];
    const float* step_w = (const float*)d_in[4];
    const float* step_b = (const float*)d_in[5];
    const float* shift  = (const float*)d_in[6];
    float* out = (float*)d_out;

    char*  xq  = (char*)d_ws;
    char*  wq2 = xq + XQ_BYTES;
    float* bi  = (float*)(wq2 + WQ_BYTES);

    fused_prep_kernel<<<2250, 256, 0, stream>>>(x, w, bias, step_x, step_w,
                                                step_b, shift, xq, wq2, bi);
    conv_mfma_kernel<<<640, 256, 0, stream>>>(xq, wq2, bi, shift, out);
}

// Round 4
// 211.051 us; speedup vs baseline: 1.0774x; 1.0774x over previous
//
#include <hip/hip_runtime.h>

typedef int v4i __attribute__((ext_vector_type(4)));

#define QMAX 127.0f

// ---- workspace layout ----
// xq  : int8 padded, swizzled [16][66][66 px][5 c5][4 slots][16]
//       slot s of (col,c5) holds logical ci-chunk s ^ ((col>>1)&3)
// wq2 : int8 fragment-order [9][5][20cog][64lane][16]
// bi  : float [320]
#define XQ_BYTES 22302720
#define WQ_BYTES 921600

__device__ __forceinline__ float clampf(float v, float lo, float hi) {
    return fminf(fmaxf(v, lo), hi);
}

// Bit-exact fast round(v/step): reciprocal multiply, exact-division fallback
// only near half-integer boundaries (trigger ~7e-4; 50x error margin).
__device__ __forceinline__ float qround(float v, float step, float inv) {
    float t = v * inv;
    float r = rintf(t);
    float d = fabsf(t - r);
    if (fabsf(d - 0.5f) < fabsf(t) * 1e-5f + 1e-5f)
        r = rintf(v / step);
    return r;
}

__device__ __forceinline__ void gload_lds16(const char* g, char* l) {
    __builtin_amdgcn_global_load_lds(
        (const __attribute__((address_space(1))) void*)g,
        (__attribute__((address_space(3))) void*)l, 16, 0, 0);
}

__device__ __forceinline__ v4i mfma_i8(v4i a, v4i b, v4i c) {
    return __builtin_amdgcn_mfma_i32_16x16x64_i8(a, b, c, 0, 0, 0);
}

// ---------------------------------------------------------------------------
// Fused producer kernel:
//   blocks [0,1024)    : x quantize (block = (h,b)), long pole -> first
//   blocks [1024,1124) : wq2 quantize, LDS-staged coalesced transform
//   blocks [1124,1449) : xq halo zeroing
//   block  1449        : bias requant
// ---------------------------------------------------------------------------
__global__ __launch_bounds__(256) void fused_prep_kernel(
    const float* __restrict__ x, const float* __restrict__ w,
    const float* __restrict__ bias,
    const float* __restrict__ step_x_p, const float* __restrict__ step_w_p,
    const float* __restrict__ step_b_p, const float* __restrict__ shift_p,
    char* __restrict__ xq, char* __restrict__ wq2, float* __restrict__ bi)
{
    // x-quant uses F as [64][65]; wq uses F as [16][577] (36,928 B)
    __shared__ float F[16 * 577];
    const int bid = blockIdx.x;
    const int t = threadIdx.x;

    if (bid < 1024) {
        // ---- x quantize: one block per (h,b); writes row h+1 interior ----
        const int h = bid & 63;
        const int b = bid >> 6;
        const float step = *step_x_p;
        const float inv  = 1.0f / step;
        const int wcol = t >> 2;       // output col-1 (0..63)
        const int cg   = t & 3;        // logical 16-ci chunk within c5
        v4i vals[5];

        for (int c5 = 0; c5 < 5; ++c5) {
            {
                const int r = t >> 4, c = (t & 15) * 4;
                const float* src = x + (((size_t)(b * 320 + c5 * 64) * 64 + h) * 64);
#pragma unroll
                for (int i = 0; i < 4; ++i) {
                    const int row = r + i * 16;
                    *(float4*)&F[row * 65 + c] =
                        *(const float4*)(src + (size_t)row * 4096 + c);
                }
            }
            __syncthreads();
            int dws[4];
#pragma unroll
            for (int j = 0; j < 4; ++j) {
                int word = 0;
#pragma unroll
                for (int k = 0; k < 4; ++k) {
                    float v = F[(cg * 16 + j * 4 + k) * 65 + wcol];
                    int xi = (int)clampf(qround(v, step, inv), -QMAX, QMAX);
                    word |= (xi & 0xFF) << (8 * k);
                }
                dws[j] = word;
            }
            vals[c5] = (v4i){dws[0], dws[1], dws[2], dws[3]};
            __syncthreads();
        }

        const int col = wcol + 1;
        const int key = (col >> 1) & 3;
        char* base = xq + ((size_t)(b * 66 + (h + 1)) * 66 + col) * 320;
#pragma unroll
        for (int c5 = 0; c5 < 5; ++c5)
            *(v4i*)(base + c5 * 64 + (((cg ^ key)) << 4)) = vals[c5];

    } else if (bid < 1124) {
        // ---- weight quantize, coalesced: block = (cog, c5) ----
        // Stage 16 co x 576 contiguous floats (float4 global loads), then
        // emit packed dwords in wq2 fragment order (coalesced 4B stores).
        const int blk = bid - 1024;      // 0..99
        const int cog = blk / 5;         // 0..19
        const int c5  = blk - cog * 5;   // 0..4
        const int co0 = cog * 16;
        const float step = *step_w_p;
        const float inv  = 1.0f / step;

        for (int idx = t; idx < 2304; idx += 256) {
            const int co_l = idx / 144;
            const int m4   = idx - co_l * 144;
            const float4 v = *(const float4*)(
                w + (size_t)(co0 + co_l) * 2880 + c5 * 576 + m4 * 4);
            float* dst = &F[co_l * 577 + m4 * 4];
            dst[0] = v.x; dst[1] = v.y; dst[2] = v.z; dst[3] = v.w;
        }
        __syncthreads();

        // dword d = t within each 1024B chunk: lane = t>>2, j = (t&3)*4 + k
        const int co_l = (t >> 2) & 15;            // co within cog
        const int cib  = (t >> 6) * 16 + (t & 3) * 4;  // ci_local base
        char* dst = wq2 + (size_t)(c5 * 20 + cog) * 1024 + t * 4;
#pragma unroll
        for (int p = 0; p < 9; ++p) {
            int word = 0;
#pragma unroll
            for (int k = 0; k < 4; ++k) {
                float v = F[co_l * 577 + (cib + k) * 9 + p];
                int q = (int)clampf(qround(v, step, inv), -QMAX, QMAX);
                word |= (q & 0xFF) << (8 * k);
            }
            *(int*)(dst + (size_t)p * 102400) = word;
        }
    } else if (bid < 1449) {
        // ---- halo zeroing ----
        int tid = (bid - 1124) * 256 + t;
        if (tid < 83200) {
            int b = tid / 5200;
            int r = tid - b * 5200;
            int px = r / 20;
            int ck = (r - px * 20) * 16;
            int row, col;
            if (px < 66)       { row = 0;  col = px; }
            else if (px < 132) { row = 65; col = px - 66; }
            else { int e = px - 132; row = 1 + (e >> 1); col = (e & 1) * 65; }
            size_t off = ((size_t)(b * 66 + row) * 66 + col) * 320 + ck;
            v4i z = {0, 0, 0, 0};
            *(v4i*)&xq[off] = z;
        }
    } else {
        // ---- bias requant ----
        const float step_b = *step_b_p;
        const float xs = 1.0f / *step_x_p;
        const float ws = 1.0f / *step_w_p;
        const float shift = *shift_p;
#pragma unroll
        for (int co = t; co < 320; co += 256) {
            float b_deq = clampf(rintf(bias[co] / step_b), -QMAX, QMAX) * step_b;
            float v = ((b_deq * shift) * xs) * ws;
            bi[co] = clampf(rintf(v), -QMAX, QMAX);
        }
    }
}

// ---------------------------------------------------------------------------
// Implicit-GEMM conv, v_mfma_i32_16x16x64_i8.  (round-1 structure, proven)
// Block = 4 waves (256 thr); wave tile 64co x 64px (1 output row) -> acc 64
// AGPR; launch_bounds(256,3) -> 3 waves/SIMD, 3 blocks/CU.
// Grid 1280, XCD-locality remap: id%8 = (ptile&7) -> the 5 co-tiles of a
// ptile run adjacent in time on one XCD -> xq L2-hot across co-tiles
// (FETCH 117MB -> 25.7MB measured).
// NOTE (round-3 post-mortem): do NOT pair ptiles per block — 640 blocks =
// 2.5/CU avg killed TLP (MfmaUtil 42->31%) and doubled L2 working set
// (FETCH +13MB, WRITE +16MB). TLP across blocks > per-block pipelining here.
// ---------------------------------------------------------------------------
__global__ __launch_bounds__(256, 3) void conv_mfma_kernel(
    const char* __restrict__ xq, const char* __restrict__ wq2,
    const float* __restrict__ bi, const float* __restrict__ shift_p,
    float* __restrict__ out)
{
    __shared__ __attribute__((aligned(16))) char B_lds[2][25344]; // 6 rows x 66 x 64

    const int t  = threadIdx.x;
    const int id = blockIdx.x;           // 0..1279
    // id = (ptile&7) + 8*bx + 40*(ptile>>3)  -- invert:
    const int g  = id / 40;
    const int r  = id - g * 40;
    const int bx = r >> 3;               // co tile 0..4
    const int ptile = (g << 3) | (r & 7);

    const int co0 = bx * 64;
    const int b  = ptile >> 4;
    const int h0 = (ptile & 15) * 4;

    const int wave = t >> 6, lane = t & 63;
    const int quad = lane >> 4, l15 = lane & 15;

    const char* xbase = xq + ((size_t)(b * 66 + h0) * 66) * 320;

    v4i acc[4][4] = {};

    // prologue: stage c5=0 into buffer 0
    for (int c = t; c < 1584; c += 256) {
        const char* gp = xbase + (c >> 2) * 320 + ((c & 3) << 4);
        gload_lds16(gp, &B_lds[0][(c - lane) * 16]);
    }
    __syncthreads();

    for (int c5 = 0; c5 < 5; ++c5) {
        // issue next stage's DMA first (lands in the other buffer; drained by
        // the barrier AFTER this c5's compute -> fully overlapped)
        if (c5 < 4) {
            const int ci0 = (c5 + 1) * 64;
            char* dst = B_lds[(c5 + 1) & 1];
            for (int c = t; c < 1584; c += 256) {
                const char* gp = xbase + (c >> 2) * 320 + ci0 + ((c & 3) << 4);
                gload_lds16(gp, &dst[(c - lane) * 16]);
            }
        }

        const char* Bc = B_lds[c5 & 1];
        const char* wp = wq2 + (c5 * 20 + bx * 4) * 1024 + lane * 16;

        // A double-buffer: prefetch p+1's 4 fragments while p's MFMAs run.
        v4i areg[2][4];
#pragma unroll
        for (int cs = 0; cs < 4; ++cs)
            areg[0][cs] = *(const v4i*)(wp + 0 * 102400 + cs * 1024);

#pragma unroll
        for (int p = 0; p < 9; ++p) {
            const int dh = p / 3, dw = p - dh * 3;
            if (p < 8) {
#pragma unroll
                for (int cs = 0; cs < 4; ++cs)
                    areg[(p + 1) & 1][cs] =
                        *(const v4i*)(wp + (p + 1) * 102400 + cs * 1024);
            }
            const int prow = wave + dh;
            auto bread = [&](int i) -> v4i {
                const int col = i * 16 + l15 + dw;
                const int key = (col >> 1) & 3;
                return *(const v4i*)&Bc[(prow * 66 + col) * 64 +
                                        ((quad ^ key) << 4)];
            };
            v4i bf = bread(0);
#pragma unroll
            for (int i = 0; i < 4; ++i) {
                v4i bcur = bf;
                if (i < 3) bf = bread(i + 1);
                __builtin_amdgcn_s_setprio(1);
#pragma unroll
                for (int cs = 0; cs < 4; ++cs)
                    acc[cs][i] = mfma_i8(areg[p & 1][cs], bcur, acc[cs][i]);
                __builtin_amdgcn_s_setprio(0);
            }
        }
        __syncthreads();
    }

    // epilogue: y_shift = clip(rint(y*shift)); out = clip(y_shift + b_int8)
    const float shift = *shift_p;
    const int h = h0 + wave;
#pragma unroll
    for (int cs = 0; cs < 4; ++cs) {
#pragma unroll
        for (int reg = 0; reg < 4; ++reg) {
            const int co = co0 + cs * 16 + quad * 4 + reg;
            const float bv = bi[co];
            float* orow = out + (((size_t)(b * 320 + co) * 64) + h) * 64;
#pragma unroll
            for (int i = 0; i < 4; ++i) {
                float y  = (float)acc[cs][i][reg];
                float ys = clampf(rintf(y * shift), -QMAX, QMAX);
                orow[i * 16 + l15] = clampf(ys + bv, -QMAX, QMAX);
            }
        }
    }
}

extern "C" void kernel_launch(void* const* d_in, const int* in_sizes, int n_in,
                              void* d_out, int out_size, void* d_ws, size_t ws_size,
                              hipStream_t stream) {
    const float* x      = (const float*)d_in[0];
    const float* w      = (const float*)d_in[1];
    const float* bias   = (const float*)d_in[2];
    const float* step_x = (const float*)d_in[3];
    const float* step_w = (const float*)d_in[4];
    const float* step_b = (const float*)d_in[5];
    const float* shift  = (const float*)d_in[6];
    float* out = (float*)d_out;

    char*  xq  = (char*)d_ws;
    char*  wq2 = xq + XQ_BYTES;
    float* bi  = (float*)(wq2 + WQ_BYTES);

    fused_prep_kernel<<<1450, 256, 0, stream>>>(x, w, bias, step_x, step_w,
                                                step_b, shift, xq, wq2, bi);
    conv_mfma_kernel<<<1280, 256, 0, stream>>>(xq, wq2, bi, shift, out);
}